// Round 1
// 700.153 us; speedup vs baseline: 1.0245x; 1.0245x over previous
//
#include <hip/hip_runtime.h>
#include <hip/hip_bf16.h>

#define BB 8
#define TT 4096
#define CC 1024
#define SS 512

typedef __bf16 bf16x8 __attribute__((ext_vector_type(8)));
typedef float f32x4 __attribute__((ext_vector_type(4)));
typedef unsigned short u16x8 __attribute__((ext_vector_type(8)));

__device__ __forceinline__ float bf2f(unsigned short u) {
  union { unsigned int i; float f; } x; x.i = ((unsigned int)u) << 16; return x.f;
}
__device__ __forceinline__ unsigned short f2bf(float f) {
  __hip_bfloat16 h = __float2bfloat16(f);
  unsigned short u; __builtin_memcpy(&u, &h, 2); return u;
}

// ---------------------------------------------------------------------------
// fp32 -> bf16 convert (+ optional transposed copy, + optional fp32 copy used
// to pre-initialize the state outputs with the residual). grid (R/64, Cd/64, B),
// block (64,4). in [R][Cd] fp32 -> out_rm [R][Cd] bf16, out_t [Cd][R] bf16,
// out_f32 [R][Cd] fp32.
// ---------------------------------------------------------------------------
__global__ void cvt_transpose(const float* __restrict__ in,
                              unsigned short* __restrict__ out_rm,
                              unsigned short* __restrict__ out_t,
                              float* __restrict__ out_f32,
                              int R, int Cd) {
  __shared__ float tile[64][65];
  const long bo = (long)blockIdx.z * R * Cd;
  const int r0 = blockIdx.x * 64, c0 = blockIdx.y * 64;
  const int tx = threadIdx.x, ty = threadIdx.y;
#pragma unroll
  for (int i = 0; i < 16; ++i) {
    int r = ty + i * 4;
    float v = in[bo + (long)(r0 + r) * Cd + c0 + tx];
    tile[r][tx] = v;
    out_rm[bo + (long)(r0 + r) * Cd + c0 + tx] = f2bf(v);
    if (out_f32 != nullptr) out_f32[bo + (long)(r0 + r) * Cd + c0 + tx] = v;
  }
  if (out_t != nullptr) {
    __syncthreads();
#pragma unroll
    for (int i = 0; i < 16; ++i) {
      int c = ty + i * 4;
      out_t[bo + (long)(c0 + c) * R + r0 + tx] = f2bf(tile[tx][c]);
    }
  }
}

// ---------------------------------------------------------------------------
// bf16 tile transpose: in [Rin][Cin] (batch stride sIn) -> out [Cin][Rin]
// (batch stride sOut). grid (Rin/64, Cin/64, B), block 256 flat.
// ---------------------------------------------------------------------------
__global__ void transpose_bf16(const unsigned short* __restrict__ in,
                               unsigned short* __restrict__ out,
                               int Rin, int Cin, long sIn, long sOut) {
  __shared__ unsigned short tile[64][72];  // stride 72: keeps 16B alignment
  const long bi = (long)blockIdx.z * sIn;
  const long bo = (long)blockIdx.z * sOut;
  const int r0 = blockIdx.x * 64, c0 = blockIdx.y * 64;
  const int tid = threadIdx.x;
  const int lr = tid >> 3;
  const int lc = (tid & 7) * 8;
#pragma unroll
  for (int p = 0; p < 2; ++p) {
    int r = lr + p * 32;
    *(u16x8*)&tile[r][lc] = *(const u16x8*)&in[bi + (long)(r0 + r) * Cin + c0 + lc];
  }
  __syncthreads();
#pragma unroll
  for (int p = 0; p < 2; ++p) {
    int s = lr + p * 32;
    u16x8 val;
#pragma unroll
    for (int j = 0; j < 8; ++j) val[j] = tile[lc + j][s];
    *(u16x8*)&out[bo + (long)(c0 + s) * Rin + r0 + lc] = val;
  }
}

// ---------------------------------------------------------------------------
// In-place row softmax over bf16 rows of length ROWLEN. One wave per row,
// 4 rows per 256-thread block. grid = total_rows/4.
// ---------------------------------------------------------------------------
template <int ROWLEN>
__global__ __launch_bounds__(256) void row_softmax(unsigned short* __restrict__ sc) {
  constexpr int NV = ROWLEN / 512;  // 16B vectors per lane
  const int lane = threadIdx.x & 63;
  const long row = (long)blockIdx.x * 4 + (threadIdx.x >> 6);
  unsigned short* base = sc + row * (long)ROWLEN;
  u16x8 d[NV];
  float m = -1e30f;
#pragma unroll
  for (int v = 0; v < NV; ++v) {
    d[v] = *(const u16x8*)&base[(v * 64 + lane) * 8];
#pragma unroll
    for (int j = 0; j < 8; ++j) m = fmaxf(m, bf2f(d[v][j]));
  }
#pragma unroll
  for (int off = 32; off >= 1; off >>= 1) m = fmaxf(m, __shfl_xor(m, off, 64));
  float l = 0.f;
#pragma unroll
  for (int v = 0; v < NV; ++v) {
#pragma unroll
    for (int j = 0; j < 8; ++j) {
      float e = __expf(bf2f(d[v][j]) - m);
      l += e;
      d[v][j] = f2bf(e);
    }
  }
#pragma unroll
  for (int off = 32; off >= 1; off >>= 1) l += __shfl_xor(l, off, 64);
  const float inv = 1.f / l;
#pragma unroll
  for (int v = 0; v < NV; ++v) {
    u16x8 o;
#pragma unroll
    for (int j = 0; j < 8; ++j) o[j] = f2bf(bf2f(d[v][j]) * inv);
    *(u16x8*)&base[(v * 64 + lane) * 8] = o;
  }
}

// ---------------------------------------------------------------------------
// GEMM: out[M,N] = alpha * A[M,K] @ Bt[N,K]^T. bf16 in, fp32 acc.
// m97 structure: 128x128 tile, BK=64, 4 waves in 2x2, each 4x4 of 16x16x32
// MFMA; global->LDS via width-16 global_load_lds (wave-uniform base+lane*16).
//
// Extensions vs previous round:
//  - A2/halfM: row-blocks with m0 >= halfM read A2 instead (fused k|v scores).
//  - Cout2/halfM: row-blocks with m0 >= halfM write Cout2 (fused kt|vt update).
//    Tiles never straddle halfM (128 | 512), so selection is block-uniform.
//  - kshift: split-K. blockIdx.z = (batch << kshift) | kchunk; each chunk
//    covers K>>kshift and (ATOMIC) accumulates into a resid-pre-initialized
//    fp32 output via HW global_atomic_add_f32. Fixes the 1-block/CU occupancy
//    collapse of the K=4096 state-update GEMMs (measured 10% occupancy).
// grid (N/128, M/128, B<<kshift), block 256. M,N mult of 128; Kchunk mult 64.
// ---------------------------------------------------------------------------
template <bool OUT_BF16, bool ATOMIC>
__global__ __launch_bounds__(256) void gemm_bt(
    const unsigned short* __restrict__ A,
    const unsigned short* __restrict__ A2, int lda, long sA,
    const unsigned short* __restrict__ Bt, int ldb, long sB,
    void* __restrict__ Cout, void* __restrict__ Cout2, int ldc, long sC,
    float alpha, int M, int N, int K, int halfM, int kshift) {
  __shared__ unsigned short As[128 * 64];
  __shared__ unsigned short Bs[128 * 64];
  const int zb = blockIdx.z >> kshift;
  const int kch = blockIdx.z & ((1 << kshift) - 1);
  const int Kc = K >> kshift;
  const int kstart = kch * Kc;
  const int kend = kstart + Kc;
  const int m0full = blockIdx.y * 128;
  const bool hi = m0full >= halfM;
  const unsigned short* Ab = ((hi && A2 != nullptr) ? A2 : A) + (long)zb * sA;
  const int mA = (hi && A2 != nullptr) ? m0full - halfM : m0full;
  void* Cbase = (hi && Cout2 != nullptr) ? Cout2 : Cout;
  const int mC = (hi && Cout2 != nullptr) ? m0full - halfM : m0full;
  const unsigned short* Bb = Bt + (long)zb * sB;
  const int n0 = blockIdx.x * 128;
  const int tid = threadIdx.x;
  const int lane = tid & 63;
  const int wm = (tid >> 6) & 1;
  const int wn = tid >> 7;
  const int srow = tid >> 3;        // 0..31 staging row
  const int scol = (tid & 7) * 8;   // staging col (elements)
  f32x4 zero = {0.f, 0.f, 0.f, 0.f};
  f32x4 acc[4][4];
#pragma unroll
  for (int i = 0; i < 4; ++i)
#pragma unroll
    for (int j = 0; j < 4; ++j) acc[i][j] = zero;

  for (int k0 = kstart; k0 < kend; k0 += 64) {
#pragma unroll
    for (int p = 0; p < 4; ++p) {
      int r = srow + p * 32;
      const unsigned short* g = Ab + (long)(mA + r) * lda + k0 + scol;
      __builtin_amdgcn_global_load_lds(
          (const __attribute__((address_space(1))) void*)g,
          (__attribute__((address_space(3))) void*)&As[r * 64 + scol], 16, 0, 0);
    }
#pragma unroll
    for (int p = 0; p < 4; ++p) {
      int r = srow + p * 32;
      const unsigned short* g = Bb + (long)(n0 + r) * ldb + k0 + scol;
      __builtin_amdgcn_global_load_lds(
          (const __attribute__((address_space(1))) void*)g,
          (__attribute__((address_space(3))) void*)&Bs[r * 64 + scol], 16, 0, 0);
    }
    __syncthreads();
#pragma unroll
    for (int kk = 0; kk < 2; ++kk) {
      const int kof = kk * 32 + (lane >> 4) * 8;
      bf16x8 af[4], bfr[4];
#pragma unroll
      for (int i = 0; i < 4; ++i)
        af[i] = *(const bf16x8*)&As[(wm * 64 + i * 16 + (lane & 15)) * 64 + kof];
#pragma unroll
      for (int j = 0; j < 4; ++j)
        bfr[j] = *(const bf16x8*)&Bs[(wn * 64 + j * 16 + (lane & 15)) * 64 + kof];
#pragma unroll
      for (int i = 0; i < 4; ++i)
#pragma unroll
        for (int j = 0; j < 4; ++j)
          acc[i][j] = __builtin_amdgcn_mfma_f32_16x16x32_bf16(af[i], bfr[j], acc[i][j], 0, 0, 0);
    }
    __syncthreads();
  }
  // epilogue: C/D layout col=lane&15, row=(lane>>4)*4+reg  [m89-verified]
  const int rbase = (lane >> 4) * 4;
  const int cl = lane & 15;
#pragma unroll
  for (int i = 0; i < 4; ++i)
#pragma unroll
    for (int j = 0; j < 4; ++j)
#pragma unroll
      for (int r = 0; r < 4; ++r) {
        int row = mC + wm * 64 + i * 16 + rbase + r;
        int col = n0 + wn * 64 + j * 16 + cl;
        long idx = (long)zb * sC + (long)row * ldc + col;
        float v = acc[i][j][r] * alpha;
        if (ATOMIC) {
          unsafeAtomicAdd(&((float*)Cbase)[idx], v);  // global_atomic_add_f32
        } else if (OUT_BF16) {
          ((unsigned short*)Cbase)[idx] = f2bf(v);
        } else {
          ((float*)Cbase)[idx] = v;
        }
      }
}

// ---------------------------------------------------------------------------
extern "C" void kernel_launch(void* const* d_in, const int* in_sizes, int n_in,
                              void* d_out, int out_size, void* d_ws, size_t ws_size,
                              hipStream_t stream) {
  const float* x = (const float*)d_in[0];
  const float* kin = (const float*)d_in[1];
  const float* vin = (const float*)d_in[2];

  float* att = (float*)d_out;                    // [B,T,C]
  float* kt = att + (long)BB * TT * CC;          // [B,S,C]
  float* vt = kt + (long)BB * SS * CC;           // [B,S,C]

  // Scratch: att output region (134 MB) exactly holds xb (67 MB) + xT (67 MB);
  // att is written by the LAST gemm, after all consumers of xb/xT are done.
  unsigned short* xb = (unsigned short*)d_out;         // bf16 [B,T,C]
  unsigned short* xT = xb + (long)BB * TT * CC;        // bf16 [B,C,T]

  const float scale = 0.03125f;  // 1/sqrt(1024)
  dim3 cblk(64, 4);
  const long MiB = 1024 * 1024;

  if (ws_size >= (size_t)(104 * MiB)) {
    // -------- primary path: fused k|v scores + fused k|v update (104 MiB ws)
    char* w = (char*)d_ws;
    unsigned short* sc  = (unsigned short*)w;               // [B,T,S]  32 MiB (written later)
    unsigned short* kb  = (unsigned short*)w;               // [B,S,C]   8 MiB (dead before sc)
    unsigned short* vb  = (unsigned short*)(w + 8 * MiB);   // [B,S,C]   8 MiB (dead before sc)
    unsigned short* vT  = (unsigned short*)(w + 32 * MiB);  // [B,C,S]   8 MiB
    unsigned short* pkv = (unsigned short*)(w + 40 * MiB);  // [B,2S,T] 64 MiB

    // 1-3: convert to bf16 (+ transposes, + resid pre-init of kt/vt)
    cvt_transpose<<<dim3(TT / 64, CC / 64, BB), cblk, 0, stream>>>(x, xb, xT, nullptr, TT, CC);
    cvt_transpose<<<dim3(SS / 64, CC / 64, BB), cblk, 0, stream>>>(kin, kb, nullptr, kt, SS, CC);
    cvt_transpose<<<dim3(SS / 64, CC / 64, BB), cblk, 0, stream>>>(vin, vb, vT, vt, SS, CC);

    // 4: pkv[2S,T] = scale * concat(k,v) @ x^T   (grid 2048, 4+/CU)
    gemm_bt<true, false><<<dim3(TT / 128, 2 * SS / 128, BB), 256, 0, stream>>>(
        kb, vb, CC, (long)SS * CC, xb, CC, (long)TT * CC,
        pkv, nullptr, TT, (long)2 * SS * TT, scale, 2 * SS, TT, CC, SS, 0);

    // 5: sc[T,S] = (k-half of pkv)^T  — raw scores for the att softmax
    transpose_bf16<<<dim3(SS / 64, TT / 64, BB), 256, 0, stream>>>(
        pkv, sc, SS, TT, (long)2 * SS * TT, (long)TT * SS);

    // 6: softmax over T for both k- and v-rows in one launch
    row_softmax<TT><<<BB * 2 * SS / 4, 256, 0, stream>>>(pkv);

    // 7: kt/vt += P_{k|v} @ x  (split-K=2, atomic fp32, resid pre-initialized)
    //    grid (8,8,16) = 1024 blocks -> 4 blocks/CU (was 256 blocks = 1/CU)
    gemm_bt<false, true><<<dim3(CC / 128, 2 * SS / 128, BB * 2), 256, 0, stream>>>(
        pkv, nullptr, TT, (long)2 * SS * TT, xT, TT, (long)CC * TT,
        kt, vt, CC, (long)SS * CC, 1.f, 2 * SS, CC, TT, SS, 1);

    // 8: att softmax over S
    row_softmax<SS><<<BB * TT / 4, 256, 0, stream>>>(sc);

    // 9: att = P_att @ v  — overwrites xb/xT scratch (all consumers done)
    gemm_bt<false, false><<<dim3(CC / 128, TT / 128, BB), 256, 0, stream>>>(
        sc, nullptr, SS, (long)TT * SS, vT, SS, (long)CC * SS,
        att, nullptr, CC, (long)TT * CC, 1.f, TT, CC, SS, 1 << 30, 0);
  } else {
    // -------- fallback path: 88 MiB ws (previous layout), sequential k then v,
    // still gets GEMM-4 elimination + split-K=4 occupancy fix on the updates.
    char* w = (char*)d_ws;
    unsigned short* kb = (unsigned short*)w;                // [B,S,C]  8 MiB
    unsigned short* vb = (unsigned short*)(w + 8 * MiB);    // [B,S,C]  8 MiB
    unsigned short* vT = (unsigned short*)(w + 16 * MiB);   // [B,C,S]  8 MiB
    unsigned short* sc = (unsigned short*)(w + 24 * MiB);   // [B,T,S] 32 MiB
    unsigned short* pk = (unsigned short*)(w + 56 * MiB);   // [B,S,T] 32 MiB

    cvt_transpose<<<dim3(TT / 64, CC / 64, BB), cblk, 0, stream>>>(x, xb, xT, nullptr, TT, CC);
    cvt_transpose<<<dim3(SS / 64, CC / 64, BB), cblk, 0, stream>>>(kin, kb, nullptr, kt, SS, CC);
    cvt_transpose<<<dim3(SS / 64, CC / 64, BB), cblk, 0, stream>>>(vin, vb, vT, vt, SS, CC);

    // pk[S,T] = scale * k @ x^T ; sc = pk^T (raw); softmax pk; kt += P_k @ x
    gemm_bt<true, false><<<dim3(TT / 128, SS / 128, BB), 256, 0, stream>>>(
        kb, nullptr, CC, (long)SS * CC, xb, CC, (long)TT * CC,
        pk, nullptr, TT, (long)SS * TT, scale, SS, TT, CC, 1 << 30, 0);
    transpose_bf16<<<dim3(SS / 64, TT / 64, BB), 256, 0, stream>>>(
        pk, sc, SS, TT, (long)SS * TT, (long)TT * SS);
    row_softmax<TT><<<BB * SS / 4, 256, 0, stream>>>(pk);
    gemm_bt<false, true><<<dim3(CC / 128, SS / 128, BB * 4), 256, 0, stream>>>(
        pk, nullptr, TT, (long)SS * TT, xT, TT, (long)CC * TT,
        kt, nullptr, CC, (long)SS * CC, 1.f, SS, CC, TT, 1 << 30, 2);

    // pv[S,T] (reuse pk); softmax; vt += P_v @ x
    gemm_bt<true, false><<<dim3(TT / 128, SS / 128, BB), 256, 0, stream>>>(
        vb, nullptr, CC, (long)SS * CC, xb, CC, (long)TT * CC,
        pk, nullptr, TT, (long)SS * TT, scale, SS, TT, CC, 1 << 30, 0);
    row_softmax<TT><<<BB * SS / 4, 256, 0, stream>>>(pk);
    gemm_bt<false, true><<<dim3(CC / 128, SS / 128, BB * 4), 256, 0, stream>>>(
        pk, nullptr, TT, (long)SS * TT, xT, TT, (long)CC * TT,
        vt, nullptr, CC, (long)SS * CC, 1.f, SS, CC, TT, 1 << 30, 2);

    row_softmax<SS><<<BB * TT / 4, 256, 0, stream>>>(sc);
    gemm_bt<false, false><<<dim3(CC / 128, TT / 128, BB), 256, 0, stream>>>(
        sc, nullptr, SS, (long)TT * SS, vT, SS, (long)CC * SS,
        att, nullptr, CC, (long)TT * CC, 1.f, TT, CC, SS, 1 << 30, 0);
  }
}

// Round 3
// 602.566 us; speedup vs baseline: 1.1904x; 1.1620x over previous
//
#include <hip/hip_runtime.h>
#include <hip/hip_bf16.h>

#define BB 8
#define TT 4096
#define CC 1024
#define SS 512

typedef __bf16 bf16x8 __attribute__((ext_vector_type(8)));
typedef float f32x4 __attribute__((ext_vector_type(4)));
typedef unsigned short u16x8 __attribute__((ext_vector_type(8)));

__device__ __forceinline__ float bf2f(unsigned short u) {
  union { unsigned int i; float f; } x; x.i = ((unsigned int)u) << 16; return x.f;
}
__device__ __forceinline__ unsigned short f2bf(float f) {
  __hip_bfloat16 h = __float2bfloat16(f);
  unsigned short u; __builtin_memcpy(&u, &h, 2); return u;
}

// ---------------------------------------------------------------------------
// fp32 -> bf16 convert (+ optional transposed copy, + optional fp32 copy used
// to pre-initialize the state outputs with the residual).
// ---------------------------------------------------------------------------
__global__ void cvt_transpose(const float* __restrict__ in,
                              unsigned short* __restrict__ out_rm,
                              unsigned short* __restrict__ out_t,
                              float* __restrict__ out_f32,
                              int R, int Cd) {
  __shared__ float tile[64][65];
  const long bo = (long)blockIdx.z * R * Cd;
  const int r0 = blockIdx.x * 64, c0 = blockIdx.y * 64;
  const int tx = threadIdx.x, ty = threadIdx.y;
#pragma unroll
  for (int i = 0; i < 16; ++i) {
    int r = ty + i * 4;
    float v = in[bo + (long)(r0 + r) * Cd + c0 + tx];
    tile[r][tx] = v;
    out_rm[bo + (long)(r0 + r) * Cd + c0 + tx] = f2bf(v);
    if (out_f32 != nullptr) out_f32[bo + (long)(r0 + r) * Cd + c0 + tx] = v;
  }
  if (out_t != nullptr) {
    __syncthreads();
#pragma unroll
    for (int i = 0; i < 16; ++i) {
      int c = ty + i * 4;
      out_t[bo + (long)(c0 + c) * R + r0 + tx] = f2bf(tile[tx][c]);
    }
  }
}

// ---------------------------------------------------------------------------
// bf16 tile transpose: in [Rin][Cin] (batch stride sIn) -> out [Cin][Rin].
// ---------------------------------------------------------------------------
__global__ void transpose_bf16(const unsigned short* __restrict__ in,
                               unsigned short* __restrict__ out,
                               int Rin, int Cin, long sIn, long sOut) {
  __shared__ unsigned short tile[64][72];
  const long bi = (long)blockIdx.z * sIn;
  const long bo = (long)blockIdx.z * sOut;
  const int r0 = blockIdx.x * 64, c0 = blockIdx.y * 64;
  const int tid = threadIdx.x;
  const int lr = tid >> 3;
  const int lc = (tid & 7) * 8;
#pragma unroll
  for (int p = 0; p < 2; ++p) {
    int r = lr + p * 32;
    *(u16x8*)&tile[r][lc] = *(const u16x8*)&in[bi + (long)(r0 + r) * Cin + c0 + lc];
  }
  __syncthreads();
#pragma unroll
  for (int p = 0; p < 2; ++p) {
    int s = lr + p * 32;
    u16x8 val;
#pragma unroll
    for (int j = 0; j < 8; ++j) val[j] = tile[lc + j][s];
    *(u16x8*)&out[bo + (long)(c0 + s) * Rin + r0 + lc] = val;
  }
}

// ---------------------------------------------------------------------------
// In-place row softmax over bf16 rows of length ROWLEN. One wave per row.
// ---------------------------------------------------------------------------
template <int ROWLEN>
__global__ __launch_bounds__(256) void row_softmax(unsigned short* __restrict__ sc) {
  constexpr int NV = ROWLEN / 512;
  const int lane = threadIdx.x & 63;
  const long row = (long)blockIdx.x * 4 + (threadIdx.x >> 6);
  unsigned short* base = sc + row * (long)ROWLEN;
  u16x8 d[NV];
  float m = -1e30f;
#pragma unroll
  for (int v = 0; v < NV; ++v) {
    d[v] = *(const u16x8*)&base[(v * 64 + lane) * 8];
#pragma unroll
    for (int j = 0; j < 8; ++j) m = fmaxf(m, bf2f(d[v][j]));
  }
#pragma unroll
  for (int off = 32; off >= 1; off >>= 1) m = fmaxf(m, __shfl_xor(m, off, 64));
  float l = 0.f;
#pragma unroll
  for (int v = 0; v < NV; ++v) {
#pragma unroll
    for (int j = 0; j < 8; ++j) {
      float e = __expf(bf2f(d[v][j]) - m);
      l += e;
      d[v][j] = f2bf(e);
    }
  }
#pragma unroll
  for (int off = 32; off >= 1; off >>= 1) l += __shfl_xor(l, off, 64);
  const float inv = 1.f / l;
#pragma unroll
  for (int v = 0; v < NV; ++v) {
    u16x8 o;
#pragma unroll
    for (int j = 0; j < 8; ++j) o[j] = f2bf(bf2f(d[v][j]) * inv);
    *(u16x8*)&base[(v * 64 + lane) * 8] = o;
  }
}

// ---------------------------------------------------------------------------
// 256x256 deep-pipelined GEMM: out[M,N] = alpha * A[M,K] @ Bt[N,K]^T.
// bf16 in, fp32 acc. 512 threads = 8 waves (2M x 4N), per-wave 128x64 out.
// BK=32, 4-slot LDS ring (A 4x16K + B 4x16K = 128 KiB DYNAMIC LDS), staged
// 2 tiles ahead via global_load_lds; counted s_waitcnt vmcnt(4) at tile end
// (never 0 in loop: stage t+2 in flight while stage t+1 is verified landed).
// LDS XOR-swizzle (kbyte ^= ((row>>1)&3)<<4) -> uniform granule spread on
// the b128 fragment reads; applied as pre-swizzled GLOBAL source + swizzled
// ds_read addr (linear LDS dest, rule 21). T5: setprio(1) around MFMA.
// XCD-chunked block swizzle (y-fastest decode). Grid total mult of 8.
//
//  - A2/halfM: row-blocks with m0 >= halfM read A2 (fused k|v scores).
//  - Cout2/halfM: row-blocks with m0 >= halfM write Cout2 (fused kt|vt).
//  - kshift: split-K; blockIdx.z=(batch<<kshift)|chunk; ATOMIC accumulates
//    into resid-pre-initialized fp32 output via global_atomic_add_f32.
// M,N mult of 256; (K>>kshift) mult of 32 and >= 64.
// ---------------------------------------------------------------------------
template <bool OUT_BF16, bool ATOMIC>
__global__ __launch_bounds__(512, 2) void gemm256(
    const unsigned short* __restrict__ A,
    const unsigned short* __restrict__ A2, int lda, long sA,
    const unsigned short* __restrict__ Bt, int ldb, long sB,
    void* __restrict__ Cout, void* __restrict__ Cout2, int ldc, long sC,
    float alpha, int M, int N, int K, int halfM, int kshift) {
  extern __shared__ unsigned char lds[];  // 131072 B at launch

  // ---- XCD-chunked swizzle (bijective; total % 8 == 0 in all our launches)
  const int gx = gridDim.x, gy = gridDim.y;
  int nx = blockIdx.x, ny = blockIdx.y, nz = blockIdx.z;
  {
    const int total = gx * gy * gridDim.z;
    if ((total & 7) == 0) {
      int flat = blockIdx.x + gx * (blockIdx.y + gy * blockIdx.z);
      const int chunk = total >> 3;
      flat = (flat & 7) * chunk + (flat >> 3);
      ny = flat % gy;                 // y fastest: A-panels stay L2-resident
      nx = (flat / gy) % gx;
      nz = flat / (gy * gx);
    }
  }

  const int zb = nz >> kshift;
  const int kch = nz & ((1 << kshift) - 1);
  const int Kc = K >> kshift;
  const int kstart = kch * Kc;
  const int nt = Kc >> 5;                     // K-tiles of 32
  const int m0full = ny * 256;
  const bool hi = m0full >= halfM;
  const unsigned short* Ab = ((hi && A2 != nullptr) ? A2 : A) + (long)zb * sA;
  const int mA = (hi && A2 != nullptr) ? m0full - halfM : m0full;
  void* Cbase = (hi && Cout2 != nullptr) ? Cout2 : Cout;
  const int mC = (hi && Cout2 != nullptr) ? m0full - halfM : m0full;
  const unsigned short* Bb = Bt + (long)zb * sB;
  const int n0 = nx * 256;

  const int tid = threadIdx.x;
  const int lane = tid & 63;
  const int wid = tid >> 6;
  const int wm = wid >> 2;                    // 0..1
  const int wn = wid & 3;                     // 0..3
  const int l15 = lane & 15;
  // swizzled k-byte within 64B LDS row (constant per lane)
  const int skb = (((lane >> 4) ^ ((l15 >> 1) & 3)) << 4);
  const int aoff = (wm * 128 + l15) * 64 + skb;       // + i*1024 per Mrep
  const int boff = (wn * 64 + l15) * 64 + skb;        // + j*1024 per Nrep

  // staging: 512 thr x 16B x 2 instr = 16 KiB slot; linear LDS dest
  // (wave-uniform base + lane*16), inverse-swizzled global source.
  const int srow = tid >> 2;                  // 0..127
  const int skb2 = ((tid & 3) << 4) ^ (((srow >> 1) & 3) << 4);

#define STAGE_OP(gb, ld, r0, k0, ldsoff)                                      \
  {                                                                           \
    _Pragma("unroll")                                                         \
    for (int i_ = 0; i_ < 2; ++i_) {                                          \
      const unsigned short* g_ = (gb) + (long)((r0) + i_ * 128 + srow) * (ld) \
                                 + (k0) + (skb2 >> 1);                        \
      __builtin_amdgcn_global_load_lds(                                       \
          (const __attribute__((address_space(1))) void*)g_,                  \
          (__attribute__((address_space(3))) void*)(lds + (ldsoff) +          \
                                                    i_ * 8192 + tid * 16),    \
          16, 0, 0);                                                          \
    }                                                                         \
  }

  f32x4 acc[8][4];
#pragma unroll
  for (int i = 0; i < 8; ++i)
#pragma unroll
    for (int j = 0; j < 4; ++j) acc[i][j] = (f32x4){0.f, 0.f, 0.f, 0.f};

  // prologue: stage tiles 0,1 into slots 0,1 (8 loads); require tile 0 landed
  STAGE_OP(Ab, lda, mA, kstart, 0);
  STAGE_OP(Bb, ldb, n0, kstart, 65536);
  STAGE_OP(Ab, lda, mA, kstart + 32, 16384);
  STAGE_OP(Bb, ldb, n0, kstart + 32, 65536 + 16384);
  asm volatile("s_waitcnt vmcnt(4)" ::: "memory");
  __builtin_amdgcn_s_barrier();

  for (int t = 0; t < nt; ++t) {
    const int slot = t & 3;
    const unsigned char* Al = lds + slot * 16384;
    const unsigned char* Bl = lds + 65536 + slot * 16384;
    const int ts = t + 2;
    const int ks = kstart + ((ts < nt) ? ts * 32 : 0);  // tail: dead restage of tile 0
    const int ss = ts & 3;                              // (keeps vmcnt counts uniform)

    // ---- phase A: B all 4 + A rows 0..63; stage A-part of tile t+2
    bf16x8 bfr[4], af[4];
#pragma unroll
    for (int j = 0; j < 4; ++j) bfr[j] = *(const bf16x8*)(Bl + boff + j * 1024);
#pragma unroll
    for (int i = 0; i < 4; ++i) af[i] = *(const bf16x8*)(Al + aoff + i * 1024);
    STAGE_OP(Ab, lda, mA, ks, ss * 16384);
    __builtin_amdgcn_s_barrier();
    asm volatile("s_waitcnt lgkmcnt(0)" ::: "memory");
    __builtin_amdgcn_sched_barrier(0);
    __builtin_amdgcn_s_setprio(1);
#pragma unroll
    for (int i = 0; i < 4; ++i)
#pragma unroll
      for (int j = 0; j < 4; ++j)
        acc[i][j] = __builtin_amdgcn_mfma_f32_16x16x32_bf16(af[i], bfr[j], acc[i][j], 0, 0, 0);
    __builtin_amdgcn_s_setprio(0);
    __builtin_amdgcn_s_barrier();

    // ---- phase B: A rows 64..127; stage B-part of tile t+2
    bf16x8 af2[4];
#pragma unroll
    for (int i = 0; i < 4; ++i) af2[i] = *(const bf16x8*)(Al + aoff + (i + 4) * 1024);
    STAGE_OP(Bb, ldb, n0, ks, 65536 + ss * 16384);
    __builtin_amdgcn_s_barrier();
    asm volatile("s_waitcnt lgkmcnt(0)" ::: "memory");
    __builtin_amdgcn_sched_barrier(0);
    __builtin_amdgcn_s_setprio(1);
#pragma unroll
    for (int i = 0; i < 4; ++i)
#pragma unroll
      for (int j = 0; j < 4; ++j)
        acc[i + 4][j] = __builtin_amdgcn_mfma_f32_16x16x32_bf16(af2[i], bfr[j], acc[i + 4][j], 0, 0, 0);
    __builtin_amdgcn_s_setprio(0);
    // counted: allow stage(t+2)'s 4 loads in flight; require stage(t+1) landed
    asm volatile("s_waitcnt vmcnt(4)" ::: "memory");
    __builtin_amdgcn_s_barrier();
  }
#undef STAGE_OP

  // epilogue: C/D layout col=lane&15, row=(lane>>4)*4+reg  [m89-verified]
  const int rbase = (lane >> 4) * 4;
  const int cl = lane & 15;
#pragma unroll
  for (int i = 0; i < 8; ++i)
#pragma unroll
    for (int j = 0; j < 4; ++j)
#pragma unroll
      for (int r = 0; r < 4; ++r) {
        int row = mC + wm * 128 + i * 16 + rbase + r;
        int col = n0 + wn * 64 + j * 16 + cl;
        long idx = (long)zb * sC + (long)row * ldc + col;
        float v = acc[i][j][r] * alpha;
        if (ATOMIC) {
          unsafeAtomicAdd(&((float*)Cbase)[idx], v);  // global_atomic_add_f32
        } else if (OUT_BF16) {
          ((unsigned short*)Cbase)[idx] = f2bf(v);
        } else {
          ((float*)Cbase)[idx] = v;
        }
      }
}

// ---------------------------------------------------------------------------
extern "C" void kernel_launch(void* const* d_in, const int* in_sizes, int n_in,
                              void* d_out, int out_size, void* d_ws, size_t ws_size,
                              hipStream_t stream) {
  const float* x = (const float*)d_in[0];
  const float* kin = (const float*)d_in[1];
  const float* vin = (const float*)d_in[2];

  // One-time opt-in for 128 KiB dynamic LDS on the gemm256 instantiations.
  // Host-side API (not a stream op) — graph-capture safe.
  static bool lds_opted = false;
  if (!lds_opted) {
    (void)hipFuncSetAttribute(
        reinterpret_cast<const void*>(&gemm256<true, false>),
        hipFuncAttributeMaxDynamicSharedMemorySize, 131072);
    (void)hipFuncSetAttribute(
        reinterpret_cast<const void*>(&gemm256<false, true>),
        hipFuncAttributeMaxDynamicSharedMemorySize, 131072);
    (void)hipFuncSetAttribute(
        reinterpret_cast<const void*>(&gemm256<false, false>),
        hipFuncAttributeMaxDynamicSharedMemorySize, 131072);
    lds_opted = true;
  }

  float* att = (float*)d_out;                    // [B,T,C]
  float* kt = att + (long)BB * TT * CC;          // [B,S,C]
  float* vt = kt + (long)BB * SS * CC;           // [B,S,C]

  // Scratch: att output region (134 MB) exactly holds xb (67 MB) + xT (67 MB);
  // att is written by the LAST gemm, after all consumers of xb/xT are done.
  unsigned short* xb = (unsigned short*)d_out;         // bf16 [B,T,C]
  unsigned short* xT = xb + (long)BB * TT * CC;        // bf16 [B,C,T]

  const float scale = 0.03125f;  // 1/sqrt(1024)
  dim3 cblk(64, 4);
  const long MiB = 1024 * 1024;
  const int GLDS = 131072;

  if (ws_size >= (size_t)(104 * MiB)) {
    // -------- primary path: fused k|v scores + fused k|v update (104 MiB ws)
    char* w = (char*)d_ws;
    unsigned short* sc  = (unsigned short*)w;               // [B,T,S]  32 MiB (written later)
    unsigned short* kb  = (unsigned short*)w;               // [B,S,C]   8 MiB (dead before sc)
    unsigned short* vb  = (unsigned short*)(w + 8 * MiB);   // [B,S,C]   8 MiB (dead before sc)
    unsigned short* vT  = (unsigned short*)(w + 32 * MiB);  // [B,C,S]   8 MiB
    unsigned short* pkv = (unsigned short*)(w + 40 * MiB);  // [B,2S,T] 64 MiB

    cvt_transpose<<<dim3(TT / 64, CC / 64, BB), cblk, 0, stream>>>(x, xb, xT, nullptr, TT, CC);
    cvt_transpose<<<dim3(SS / 64, CC / 64, BB), cblk, 0, stream>>>(kin, kb, nullptr, kt, SS, CC);
    cvt_transpose<<<dim3(SS / 64, CC / 64, BB), cblk, 0, stream>>>(vin, vb, vT, vt, SS, CC);

    // 4: pkv[2S,T] = scale * concat(k,v) @ x^T   (grid (16,4,8)=512 blocks)
    gemm256<true, false><<<dim3(TT / 256, 2 * SS / 256, BB), 512, GLDS, stream>>>(
        kb, vb, CC, (long)SS * CC, xb, CC, (long)TT * CC,
        pkv, nullptr, TT, (long)2 * SS * TT, scale, 2 * SS, TT, CC, SS, 0);

    // 5: sc[T,S] = (k-half of pkv)^T  — raw scores for the att softmax
    transpose_bf16<<<dim3(SS / 64, TT / 64, BB), 256, 0, stream>>>(
        pkv, sc, SS, TT, (long)2 * SS * TT, (long)TT * SS);

    // 6: softmax over T for both k- and v-rows in one launch
    row_softmax<TT><<<BB * 2 * SS / 4, 256, 0, stream>>>(pkv);

    // 7: kt/vt += P_{k|v} @ x  (split-K=2, atomic fp32, resid pre-initialized)
    gemm256<false, true><<<dim3(CC / 256, 2 * SS / 256, BB * 2), 512, GLDS, stream>>>(
        pkv, nullptr, TT, (long)2 * SS * TT, xT, TT, (long)CC * TT,
        kt, vt, CC, (long)SS * CC, 1.f, 2 * SS, CC, TT, SS, 1);

    // 8: att softmax over S
    row_softmax<SS><<<BB * TT / 4, 256, 0, stream>>>(sc);

    // 9: att = P_att @ v  — overwrites xb/xT scratch (all consumers done)
    gemm256<false, false><<<dim3(CC / 256, TT / 256, BB), 512, GLDS, stream>>>(
        sc, nullptr, SS, (long)TT * SS, vT, SS, (long)CC * SS,
        att, nullptr, CC, (long)TT * CC, 1.f, TT, CC, SS, 1 << 30, 0);
  } else {
    // -------- fallback path: 88 MiB ws, sequential k then v
    char* w = (char*)d_ws;
    unsigned short* kb = (unsigned short*)w;                // [B,S,C]  8 MiB
    unsigned short* vb = (unsigned short*)(w + 8 * MiB);    // [B,S,C]  8 MiB
    unsigned short* vT = (unsigned short*)(w + 16 * MiB);   // [B,C,S]  8 MiB
    unsigned short* sc = (unsigned short*)(w + 24 * MiB);   // [B,T,S] 32 MiB
    unsigned short* pk = (unsigned short*)(w + 56 * MiB);   // [B,S,T] 32 MiB

    cvt_transpose<<<dim3(TT / 64, CC / 64, BB), cblk, 0, stream>>>(x, xb, xT, nullptr, TT, CC);
    cvt_transpose<<<dim3(SS / 64, CC / 64, BB), cblk, 0, stream>>>(kin, kb, nullptr, kt, SS, CC);
    cvt_transpose<<<dim3(SS / 64, CC / 64, BB), cblk, 0, stream>>>(vin, vb, vT, vt, SS, CC);

    gemm256<true, false><<<dim3(TT / 256, SS / 256, BB), 512, GLDS, stream>>>(
        kb, nullptr, CC, (long)SS * CC, xb, CC, (long)TT * CC,
        pk, nullptr, TT, (long)SS * TT, scale, SS, TT, CC, 1 << 30, 0);
    transpose_bf16<<<dim3(SS / 64, TT / 64, BB), 256, 0, stream>>>(
        pk, sc, SS, TT, (long)SS * TT, (long)TT * SS);
    row_softmax<TT><<<BB * SS / 4, 256, 0, stream>>>(pk);
    gemm256<false, true><<<dim3(CC / 256, SS / 256, BB * 4), 512, GLDS, stream>>>(
        pk, nullptr, TT, (long)SS * TT, xT, TT, (long)CC * TT,
        kt, nullptr, CC, (long)SS * CC, 1.f, SS, CC, TT, 1 << 30, 2);

    gemm256<true, false><<<dim3(TT / 256, SS / 256, BB), 512, GLDS, stream>>>(
        vb, nullptr, CC, (long)SS * CC, xb, CC, (long)TT * CC,
        pk, nullptr, TT, (long)SS * TT, scale, SS, TT, CC, 1 << 30, 0);
    row_softmax<TT><<<BB * SS / 4, 256, 0, stream>>>(pk);
    gemm256<false, true><<<dim3(CC / 256, SS / 256, BB * 4), 512, GLDS, stream>>>(
        pk, nullptr, TT, (long)SS * TT, xT, TT, (long)CC * TT,
        vt, nullptr, CC, (long)SS * CC, 1.f, SS, CC, TT, 1 << 30, 2);

    row_softmax<SS><<<BB * TT / 4, 256, 0, stream>>>(sc);
    gemm256<false, false><<<dim3(CC / 256, TT / 256, BB), 512, GLDS, stream>>>(
        sc, nullptr, SS, (long)TT * SS, vT, SS, (long)CC * SS,
        att, nullptr, CC, (long)TT * CC, 1.f, TT, CC, SS, 1 << 30, 0);
  }
}